// Round 5
// baseline (560.717 us; speedup 1.0000x reference)
//
#include <hip/hip_runtime.h>
#include <hip/hip_bf16.h>

typedef __attribute__((ext_vector_type(8))) short short8;
typedef __attribute__((ext_vector_type(4))) float floatx4;
typedef unsigned short u16;
typedef unsigned int u32;

#define BATCH 16
#define HH 224
#define WW 224
#define ICN 64
#define OCN 128

// conv tile: 2 output rows x 40 cols per WG (6 w-chunks; last overlaps, stores idempotent)
#define MT 80
#define AR 168            // 4 padded input rows x 42 padded cols
#define A_BYTES (AR*128)  // 21504

#define WB_BYTES ((size_t)OCN*ICN*9*2)         // 147,456

__device__ __forceinline__ u16 f2bf(float f) {
  __hip_bfloat16 h = __float2bfloat16(f);
  return *reinterpret_cast<u16*>(&h);
}

__device__ __forceinline__ float fast_tanh(float x) {
  float e = __expf(2.0f * x);    // x>>0 -> 1, x<<0 -> -1, inf-safe
  return 1.0f - 2.0f / (e + 1.0f);
}

// ---------- inline container-dtype detect (verified R3) ----------
// bf16 containers: both u16 halves of words 0..63 have sane bf16 exponents.
// Wave-parallel: lane i checks word i&63; two 64-bit ballots + popcount.
__device__ __forceinline__ bool detect_isbf(const u32* __restrict__ xw, int tid) {
  u32 w = xw[tid & 63];
  int e0 = (w >> 7) & 0xFF;
  int e1 = (w >> 23) & 0xFF;
  unsigned long long b0 = __ballot(e0 >= 90 && e0 <= 160);
  unsigned long long b1 = __ballot(e1 >= 90 && e1 <= 160);
  return (__popcll(b0) + __popcll(b1)) >= 120;
}

// ---------- prep_w: OIHW (fp32 or bf16) -> [oc][tap*64+ic] bf16 ----------
__global__ __launch_bounds__(256) void prep_w(const void* __restrict__ wv_, u16* __restrict__ wb,
                                              const void* __restrict__ xv) {
  const bool isbf = detect_isbf((const u32*)xv, threadIdx.x);
  int o = blockIdx.x*256 + threadIdx.x;   // 0..73727
  int oc = o / 576;
  int k = o - oc*576;
  int tap = k >> 6;
  int ic = k & 63;
  int src = oc*576 + ic*9 + tap;
  wb[o] = isbf ? ((const u16*)wv_)[src] : f2bf(((const float*)wv_)[src]);
}

// ---------- fused staging + conv3x3 + bias + min_oc + double tanh ----------
// MERGED: reads x in NCHW directly (no prep_x, no xb workspace round-trip).
// Staging thread map: p = tid&31 (ch-pair), dyi = (tid>>5)&3 (padded row),
// half = tid>>7 (col halves of 21). Each thread converts 2 channels x 21 cols
// to bf16 pairs and writes u32s into the SAME swizzled LDS layout the verified
// MFMA core reads: row r = dyi*42 + wloc; u32 at r*128 + ((p>>2)^(r&7))*16 + (p&3)*4.
// Write conflicts: per column, 32 lanes (p=0..31) hit 32 distinct banks. Zero-pad
// semantics identical to old prep_x (h outside [0,224) -> 0; col outside -> 0).
// Interior w-chunks (wsel 1..4) use aligned vector loads; w-edges scalar+clamp.
// Tap loop + epilogue byte-identical to the R3-verified kernel.
__global__ __launch_bounds__(256, 4) void conv_min_kernel(
    const void* __restrict__ xv, const u16* __restrict__ wb,
    const void* __restrict__ biasv, void* __restrict__ outv)
{
  __shared__ __align__(16) char ldsA[A_BYTES];   // 168 rows x 128 B
  float* minbuf = (float*)ldsA;                  // aliased post-loop (barrier-fenced)

  const int tid = threadIdx.x;
  const bool isbf = detect_isbf((const u32*)xv, tid);
  const int wv = tid >> 6;
  const int lane = tid & 63;
  const int m15 = lane & 15;
  const int quad = lane >> 4;

  int bid = blockIdx.x;
  const int wsel = bid % 6;
  int rest = bid / 6;
  const int h0 = (rest % 112) * 2;
  const int b = rest / 112;
  const int w0 = (wsel < 5) ? wsel*40 : 184;     // last chunk overlaps; stores idempotent

  // ---- staging: NCHW (fp32 or bf16 container) -> swizzled bf16 LDS
  const int p    = tid & 31;          // channel pair (ch 2p, 2p+1)
  const int uu   = tid >> 5;
  const int dyi  = uu & 3;            // padded input row 0..3
  const int half = uu >> 2;           // col half: [half*21, half*21+21)
  const int h    = h0 - 1 + dyi;
  const bool hv  = (h >= 0) && (h < HH);
  const int r0   = dyi*42 + half*21;
  const int pb   = (p & 3) * 4;       // byte within 16-B chunk
  const int pc   = p >> 2;            // chunk index 0..7

#define STW(j, val) { int r_ = r0 + (j); \
    *(u32*)(ldsA + r_*128 + ((pc ^ (r_ & 7))*16) + pb) = (val); }

  if (!hv) {
    #pragma unroll
    for (int j = 0; j < 21; ++j) STW(j, 0u);
  } else {
    const size_t ch0 = ((size_t)(b*ICN + 2*p)*HH + h)*WW;
    const bool wint = (wsel >= 1) && (wsel <= 4);   // cols w0-1..w0+40 all in [0,224)
    if (isbf) {
      const u16* rp0 = (const u16*)xv + ch0;
      const u16* rp1 = rp0 + (size_t)HH*WW;
      if (wint) {
        // window [w0-8, w0+56): 16-B aligned; per half: 4 short8 from W + half*24
        const u16* s0 = rp0 + (w0 - 8) + half*24;
        const u16* s1 = rp1 + (w0 - 8) + half*24;
        short8 qa[4], qb[4];
        #pragma unroll
        for (int k2 = 0; k2 < 4; ++k2) {
          qa[k2] = *(const short8*)(s0 + k2*8);
          qb[k2] = *(const short8*)(s1 + k2*8);
        }
        if (half == 0) {              // li = (w0-1+j) - (w0-8) = j+7
          #pragma unroll
          for (int j = 0; j < 21; ++j) {
            const int li = j + 7;
            u32 vv = (u32)(u16)qa[li>>3][li&7] | ((u32)(u16)qb[li>>3][li&7] << 16);
            STW(j, vv);
          }
        } else {                      // li = (w0+20+j) - (w0-8+24) = j+4
          #pragma unroll
          for (int j = 0; j < 21; ++j) {
            const int li = j + 4;
            u32 vv = (u32)(u16)qa[li>>3][li&7] | ((u32)(u16)qb[li>>3][li&7] << 16);
            STW(j, vv);
          }
        }
      } else {                        // w-edge: scalar clamped loads + select
        #pragma unroll
        for (int j = 0; j < 21; ++j) {
          int wg = w0 - 1 + half*21 + j;
          int wc = min(max(wg, 0), WW-1);
          bool vld = (wg >= 0) && (wg < WW);
          u16 a = rp0[wc];
          u16 c = rp1[wc];
          u32 vv = vld ? ((u32)a | ((u32)c << 16)) : 0u;
          STW(j, vv);
        }
      }
    } else {
      const float* rp0 = (const float*)xv + ch0;
      const float* rp1 = rp0 + (size_t)HH*WW;
      if (wint) {
        // window [w0-4, w0+44): 16-B aligned; per half: 6 float4 from W + half*24
        const float* s0 = rp0 + (w0 - 4) + half*24;
        const float* s1 = rp1 + (w0 - 4) + half*24;
        floatx4 qa[6], qb[6];
        #pragma unroll
        for (int k2 = 0; k2 < 6; ++k2) {
          qa[k2] = *(const floatx4*)(s0 + k2*4);
          qb[k2] = *(const floatx4*)(s1 + k2*4);
        }
        if (half == 0) {              // li = (w0-1+j) - (w0-4) = j+3
          #pragma unroll
          for (int j = 0; j < 21; ++j) {
            const int li = j + 3;
            u32 vv = (u32)f2bf(qa[li>>2][li&3]) | ((u32)f2bf(qb[li>>2][li&3]) << 16);
            STW(j, vv);
          }
        } else {                      // li = (w0+20+j) - (w0-4+24) = j
          #pragma unroll
          for (int j = 0; j < 21; ++j) {
            const int li = j;
            u32 vv = (u32)f2bf(qa[li>>2][li&3]) | ((u32)f2bf(qb[li>>2][li&3]) << 16);
            STW(j, vv);
          }
        }
      } else {                        // w-edge: scalar clamped loads + select
        #pragma unroll
        for (int j = 0; j < 21; ++j) {
          int wg = w0 - 1 + half*21 + j;
          int wc = min(max(wg, 0), WW-1);
          bool vld = (wg >= 0) && (wg < WW);
          float a = rp0[wc];
          float c = rp1[wc];
          u32 vv = vld ? ((u32)f2bf(a) | ((u32)f2bf(c) << 16)) : 0u;
          STW(j, vv);
        }
      }
    }
  }
#undef STW

  // ---- per-lane A-row bases: pixel p = mb*16 + m15 -> base = (p/40)*42 + p%40
  int arow[5];
  #pragma unroll
  for (int mb = 0; mb < 5; ++mb) {
    int pp = mb*16 + m15;
    int ro = pp / 40;
    arow[mb] = ro*42 + (pp - ro*40);
  }

  // ---- per-lane B: row oc = wv*32 + nb*16 + m15, k-chunk = ks*4 + quad
  const u16* bbase = wb + (wv*32 + m15)*576 + quad*8;
  short8 bcur[2][2];
  #pragma unroll
  for (int nb = 0; nb < 2; ++nb)
    #pragma unroll
    for (int ks = 0; ks < 2; ++ks)
      bcur[nb][ks] = *(const short8*)(bbase + nb*16*576 + ks*32);

  floatx4 acc[5][2];
  #pragma unroll
  for (int mb = 0; mb < 5; ++mb) {
    acc[mb][0] = (floatx4){0.f,0.f,0.f,0.f};
    acc[mb][1] = (floatx4){0.f,0.f,0.f,0.f};
  }

  __syncthreads();                         // A visible to all waves

  #pragma unroll
  for (int tap = 0; tap < 9; ++tap) {
    short8 bnxt[2][2];
    if (tap < 8) {                         // prefetch next tap's B frags (L2-hit)
      #pragma unroll
      for (int nb = 0; nb < 2; ++nb)
        #pragma unroll
        for (int ks = 0; ks < 2; ++ks)
          bnxt[nb][ks] = *(const short8*)(bbase + nb*16*576 + (tap+1)*64 + ks*32);
    }
    const int dy = tap / 3;
    const int dx = tap - dy*3;
    const int rdelta = dy*42 + dx;
    #pragma unroll
    for (int ks = 0; ks < 2; ++ks) {
      const int csel = ks*4 + quad;
      short8 af[5];
      #pragma unroll
      for (int mb = 0; mb < 5; ++mb) {
        int row = arow[mb] + rdelta;
        af[mb] = *(const short8*)(ldsA + row*128 + ((csel ^ (row & 7))*16));
      }
      #pragma unroll
      for (int mb = 0; mb < 5; ++mb) {
        acc[mb][0] = __builtin_amdgcn_mfma_f32_16x16x32_bf16(af[mb], bcur[0][ks], acc[mb][0], 0, 0, 0);
        acc[mb][1] = __builtin_amdgcn_mfma_f32_16x16x32_bf16(af[mb], bcur[1][ks], acc[mb][1], 0, 0, 0);
      }
    }
    if (tap < 8) {
      #pragma unroll
      for (int nb = 0; nb < 2; ++nb)
        #pragma unroll
        for (int ks = 0; ks < 2; ++ks)
          bcur[nb][ks] = bnxt[nb][ks];
    }
  }
  __syncthreads();   // fence A reads before minbuf aliasing writes

  // ---- epilogue: +bias, min over oc, cross-lane/cross-wave min, tanh(tanh), store
  float bv0, bv1;
  if (isbf) {
    bv0 = __bfloat162float(((const __hip_bfloat16*)biasv)[wv*32 + m15]);
    bv1 = __bfloat162float(((const __hip_bfloat16*)biasv)[wv*32 + 16 + m15]);
  } else {
    bv0 = ((const float*)biasv)[wv*32 + m15];
    bv1 = ((const float*)biasv)[wv*32 + 16 + m15];
  }
  #pragma unroll
  for (int mb = 0; mb < 5; ++mb) {
    #pragma unroll
    for (int r = 0; r < 4; ++r) {
      float v = fminf(acc[mb][0][r] + bv0, acc[mb][1][r] + bv1);
      v = fminf(v, __shfl_xor(v, 1));
      v = fminf(v, __shfl_xor(v, 2));
      v = fminf(v, __shfl_xor(v, 4));
      v = fminf(v, __shfl_xor(v, 8));
      if (m15 == 0)
        minbuf[wv*MT + mb*16 + quad*4 + r] = v;   // pixel = mb*16 + quad*4 + r
    }
  }
  __syncthreads();
  if (tid < MT) {
    float v = fminf(fminf(minbuf[tid], minbuf[MT + tid]),
                    fminf(minbuf[2*MT + tid], minbuf[3*MT + tid]));
    float t = fast_tanh(fast_tanh(v));
    int ro = tid / 40;
    int co = tid - ro*40;
    size_t oi = ((size_t)(b*HH + h0 + ro))*WW + w0 + co;
    if (isbf) ((__hip_bfloat16*)outv)[oi] = __float2bfloat16(t);
    else      ((float*)outv)[oi] = t;
  }
}

extern "C" void kernel_launch(void* const* d_in, const int* in_sizes, int n_in,
                              void* d_out, int out_size, void* d_ws, size_t ws_size,
                              hipStream_t stream) {
  (void)in_sizes; (void)n_in; (void)out_size;
  if (ws_size < WB_BYTES + 16) return;

  const void* x  = d_in[0];
  const void* w  = d_in[1];
  const void* bias = d_in[2];
  u16* wb = (u16*)d_ws;

  prep_w<<<288, 256, 0, stream>>>(w, wb, x);
  conv_min_kernel<<<6*112*BATCH, 256, 0, stream>>>(x, wb, bias, d_out);
}

// Round 6
// 485.965 us; speedup vs baseline: 1.1538x; 1.1538x over previous
//
#include <hip/hip_runtime.h>
#include <hip/hip_bf16.h>

typedef __attribute__((ext_vector_type(8))) short short8;
typedef __attribute__((ext_vector_type(4))) float floatx4;
typedef unsigned short u16;
typedef unsigned int u32;

#define BATCH 16
#define HH 224
#define WW 224
#define ICN 64
#define OCN 128
#define HP 226
#define WP 226

// conv tile: 4 output rows x 40 cols per WG (6 w-chunks; last overlaps, stores idempotent)
#define MTT 160           // output px per block
#define AR6 252           // 6 padded input rows x 42 padded cols
#define A6_BYTES (AR6*128) // 32256
#define AQ6 (AR6*8)       // 2016 16-B chunks

#define NPX (BATCH*113*4)  // 7232 prep_x blocks; +288 prep_w tail blocks

#define XB_BYTES ((size_t)BATCH*HP*WP*ICN*2)   // 104,603,648
#define WB_BYTES ((size_t)OCN*ICN*9*2)         // 147,456

// async global->LDS, 16B per lane; LDS dest = wave-uniform base + lane*16
#define ASYNC16(g, l) __builtin_amdgcn_global_load_lds( \
    (const __attribute__((address_space(1))) void*)(g), \
    (__attribute__((address_space(3))) void*)(l), 16, 0, 0)

__device__ __forceinline__ u16 f2bf(float f) {
  __hip_bfloat16 h = __float2bfloat16(f);
  return *reinterpret_cast<u16*>(&h);
}

__device__ __forceinline__ float fast_tanh(float x) {
  float e = __expf(2.0f * x);    // x>>0 -> 1, x<<0 -> -1, inf-safe
  return 1.0f - 2.0f / (e + 1.0f);
}

// ---------- inline container-dtype detect (verified R3) ----------
__device__ __forceinline__ bool detect_isbf(const u32* __restrict__ xw, int tid) {
  u32 w = xw[tid & 63];
  int e0 = (w >> 7) & 0xFF;
  int e1 = (w >> 23) & 0xFF;
  unsigned long long b0 = __ballot(e0 >= 90 && e0 <= 160);
  unsigned long long b1 = __ballot(e1 >= 90 && e1 <= 160);
  return (__popcll(b0) + __popcll(b1)) >= 120;
}

// ---------- prep_all (VERBATIM from R3-verified): prep_x + prep_w tail ----------
__global__ __launch_bounds__(256) void prep_all(const void* __restrict__ xv,
                                                const void* __restrict__ wv_,
                                                u16* __restrict__ xb,
                                                u16* __restrict__ wb) {
  __shared__ u32 tile32[2][64*33];   // [w_local][ic_pair], stride 33
  const int tid = threadIdx.x;
  const bool isbf = detect_isbf((const u32*)xv, tid);
  int bid = blockIdx.x;

  if (bid >= NPX) {                  // ---- prep_w tail ----
    int o = (bid - NPX)*256 + tid;   // 0..73727
    int oc = o / 576;
    int k = o - oc*576;
    int tap = k >> 6;
    int ic = k & 63;
    int src = oc*576 + ic*9 + tap;
    wb[o] = isbf ? ((const u16*)wv_)[src] : f2bf(((const float*)wv_)[src]);
    return;
  }

  const int chunk = bid & 3;         // 4 chunks of 64 input cols
  int rest = bid >> 2;
  const int hp0 = rest % 113;        // rows hp0 and hp0+113
  const int b = rest / 113;
  const int wt = chunk * 64;
  const int icp = tid >> 3;          // ic pair 0..31
  const int oct = tid & 7;           // w octet 0..7
  const int w = wt + oct*8;
  const int ic0 = icp*2;

  #pragma unroll
  for (int t = 0; t < 2; ++t) {
    const int hp = hp0 + t*113;
    const int h = hp - 1;
    const bool valid = (h >= 0) && (h < HH) && (w < WW);
    const size_t b0 = (((size_t)(b*ICN + ic0))*HH + h)*WW + w;
    const size_t b1 = (((size_t)(b*ICN + ic0+1))*HH + h)*WW + w;
    u16 a[8], c[8];
    if (isbf) {
      short8 v0 = {0,0,0,0,0,0,0,0}, v1 = {0,0,0,0,0,0,0,0};
      if (valid) {
        v0 = *(const short8*)((const u16*)xv + b0);
        v1 = *(const short8*)((const u16*)xv + b1);
      }
      #pragma unroll
      for (int s = 0; s < 8; ++s) { a[s] = (u16)v0[s]; c[s] = (u16)v1[s]; }
    } else {
      floatx4 f0={0,0,0,0}, f1={0,0,0,0}, f2={0,0,0,0}, f3={0,0,0,0};
      if (valid) {
        const float* p0 = (const float*)xv + b0;
        const float* p1 = (const float*)xv + b1;
        f0 = *(const floatx4*)p0; f1 = *(const floatx4*)(p0+4);
        f2 = *(const floatx4*)p1; f3 = *(const floatx4*)(p1+4);
      }
      #pragma unroll
      for (int s = 0; s < 4; ++s) {
        a[s] = f2bf(f0[s]); a[4+s] = f2bf(f1[s]);
        c[s] = f2bf(f2[s]); c[4+s] = f2bf(f3[s]);
      }
    }
    #pragma unroll
    for (int s = 0; s < 8; ++s)
      tile32[t][(oct*8 + s)*33 + icp] = (u32)a[s] | ((u32)c[s] << 16);
  }
  __syncthreads();
  #pragma unroll
  for (int t = 0; t < 2; ++t) {
    const int hp = hp0 + t*113;
    #pragma unroll
    for (int p = 0; p < 2; ++p) {
      int idx = p*256 + tid;
      int wl = idx >> 3;
      int icc = idx & 7;
      int wp = wt + 1 + wl;
      if (wp < WP) {
        u32 cc[4];
        #pragma unroll
        for (int j = 0; j < 4; ++j) cc[j] = tile32[t][wl*33 + icc*4 + j];
        short8 o;
        #pragma unroll
        for (int j = 0; j < 4; ++j) { o[2*j] = (short)(cc[j] & 0xFFFF); o[2*j+1] = (short)(cc[j] >> 16); }
        *(short8*)(xb + (((size_t)(b*HP) + hp)*WP + wp)*ICN + icc*8) = o;
      }
    }
    if (chunk == 0 && tid < 8) {     // left border column wp=0
      short8 z = {0,0,0,0,0,0,0,0};
      *(short8*)(xb + (((size_t)(b*HP) + hp)*WP)*ICN + tid*8) = z;
    }
  }
}

// ---------- fused conv3x3 + bias + min_oc + double tanh (4-row / 64-oc-per-wave) ----------
// R5 model: old conv was simultaneously LDS-read-bound (~94%) and per-CU-L2-bound
// (~86%) on B re-reads. This config halves BOTH bytes/pixel:
//  - 4 waves = 2 m-groups (ig) x 2 oc-groups (jg); each wave 5 mb x 4 nb (64 oc):
//    one af ds_read_b128 now feeds 4 MFMAs (was 2) -> LDS bytes/px halved.
//  - M=160 px/block: B fragments re-read once per 160 px (was 80); the two ig-waves
//    of a jg-group issue IDENTICAL B addresses in the same tap window -> L1 shares.
//  - staging 6 input rows per 4 output rows (was 4 per 2): -25% bytes/px.
// (256,2): ~185 regs/wave (acc 80 + bcur/bnxt 64 + af 20 + addr) fits 2 waves/SIMD.
// Staging = verified ASYNC16 involution (c = slot^(r&7), linear dest q*16),
// extended to 252 LDS rows. Tap loop/epilogue structure = verified pattern.
__global__ __launch_bounds__(256, 2) void conv_min_kernel(
    const u16* __restrict__ xb, const u16* __restrict__ wb,
    const void* __restrict__ biasv, void* __restrict__ outv,
    const void* __restrict__ xv)
{
  __shared__ __align__(16) char ldsA[A6_BYTES];  // 252 rows x 128 B
  float* minbuf = (float*)ldsA;                  // aliased post-loop (barrier-fenced)

  const int tid = threadIdx.x;
  const bool isbf = detect_isbf((const u32*)xv, tid);
  const int wv = tid >> 6;
  const int lane = tid & 63;
  const int m15 = lane & 15;
  const int quad = lane >> 4;
  const int ig = wv >> 1;            // m-group: pixels ig*80 + ...
  const int jg = wv & 1;             // oc-group: oc jg*64 + ...

  int bid = blockIdx.x;
  const int wsel = bid % 6;
  int rest = bid / 6;
  const int h0 = (rest % 56) * 4;    // 4 output rows h0..h0+3
  const int b = rest / 56;
  const int w0 = (wsel < 5) ? wsel*40 : 184;     // last chunk overlaps; stores idempotent

  // ---- stage A via async global->LDS: 2016 chunks, q = it*256 + tid
  //   r = q>>3, slot = q&7; LDS dest = q*16 (linear); src chunk c = slot^(r&7)
  const char* srcb = (const char*)xb + 2*((((size_t)(b*HP) + h0)*WP)*ICN) + (size_t)w0*128;
  #pragma unroll
  for (int it = 0; it < 8; ++it) {
    if (it < 7 || tid < 224) {       // AQ6 = 2016 = 7*256 + 224
      int q = it*256 + tid;
      int r = q >> 3;
      int slot = q & 7;
      int c = slot ^ (r & 7);
      int dyi = (r * 781) >> 15;     // r/42, exact for r < 252
      int wloc = r - dyi*42;
      int off = ((dyi*WP + wloc)*ICN + c*8) * 2;
      ASYNC16(srcb + off, ldsA + it*4096 + wv*1024);
    }
  }

  // ---- per-lane A-row bases: pixel p = ig*80 + mb*16 + m15 -> (p/40)*42 + p%40
  int arow[5];
  #pragma unroll
  for (int mb = 0; mb < 5; ++mb) {
    int pp = ig*80 + mb*16 + m15;
    int ro = pp / 40;
    arow[mb] = ro*42 + (pp - ro*40);
  }

  // ---- per-lane B: row oc = jg*64 + nb*16 + m15, k-chunk = ks*4 + quad
  const u16* bbase = wb + (jg*64 + m15)*576 + quad*8;
  short8 bcur[4][2];
  #pragma unroll
  for (int nb = 0; nb < 4; ++nb)
    #pragma unroll
    for (int ks = 0; ks < 2; ++ks)
      bcur[nb][ks] = *(const short8*)(bbase + nb*16*576 + ks*32);

  floatx4 acc[5][4];
  #pragma unroll
  for (int mb = 0; mb < 5; ++mb)
    #pragma unroll
    for (int nb = 0; nb < 4; ++nb)
      acc[mb][nb] = (floatx4){0.f,0.f,0.f,0.f};

  __syncthreads();                         // drains vmcnt -> A resident

  #pragma unroll
  for (int tap = 0; tap < 9; ++tap) {
    short8 bnxt[4][2];
    if (tap < 8) {                         // prefetch next tap's B frags (L2/L1-hit)
      #pragma unroll
      for (int nb = 0; nb < 4; ++nb)
        #pragma unroll
        for (int ks = 0; ks < 2; ++ks)
          bnxt[nb][ks] = *(const short8*)(bbase + nb*16*576 + (tap+1)*64 + ks*32);
    }
    const int dy = tap / 3;
    const int dx = tap - dy*3;
    const int rdelta = dy*42 + dx;
    #pragma unroll
    for (int ks = 0; ks < 2; ++ks) {
      const int csel = ks*4 + quad;
      short8 af[5];
      #pragma unroll
      for (int mb = 0; mb < 5; ++mb) {
        int row = arow[mb] + rdelta;
        af[mb] = *(const short8*)(ldsA + row*128 + ((csel ^ (row & 7))*16));
      }
      #pragma unroll
      for (int mb = 0; mb < 5; ++mb)
        #pragma unroll
        for (int nb = 0; nb < 4; ++nb)
          acc[mb][nb] = __builtin_amdgcn_mfma_f32_16x16x32_bf16(af[mb], bcur[nb][ks], acc[mb][nb], 0, 0, 0);
    }
    if (tap < 8) {
      #pragma unroll
      for (int nb = 0; nb < 4; ++nb)
        #pragma unroll
        for (int ks = 0; ks < 2; ++ks)
          bcur[nb][ks] = bnxt[nb][ks];
    }
  }
  __syncthreads();   // fence A reads before minbuf aliasing writes

  // ---- epilogue: +bias, min over 4 nb, cross-lane min over m15 (16 oc),
  //      cross-jg min via minbuf, tanh(tanh), store
  float bv[4];
  #pragma unroll
  for (int nb = 0; nb < 4; ++nb) {
    int oc = jg*64 + nb*16 + m15;
    bv[nb] = isbf ? __bfloat162float(((const __hip_bfloat16*)biasv)[oc])
                  : ((const float*)biasv)[oc];
  }
  #pragma unroll
  for (int mb = 0; mb < 5; ++mb) {
    #pragma unroll
    for (int r = 0; r < 4; ++r) {
      float v = fminf(fminf(acc[mb][0][r] + bv[0], acc[mb][1][r] + bv[1]),
                      fminf(acc[mb][2][r] + bv[2], acc[mb][3][r] + bv[3]));
      v = fminf(v, __shfl_xor(v, 1));
      v = fminf(v, __shfl_xor(v, 2));
      v = fminf(v, __shfl_xor(v, 4));
      v = fminf(v, __shfl_xor(v, 8));
      if (m15 == 0)
        minbuf[jg*MTT + ig*80 + mb*16 + quad*4 + r] = v;  // px = ig*80+mb*16+quad*4+r
    }
  }
  __syncthreads();
  if (tid < MTT) {
    float v = fminf(minbuf[tid], minbuf[MTT + tid]);
    float t = fast_tanh(fast_tanh(v));
    int ro = tid / 40;
    int co = tid - ro*40;
    size_t oi = ((size_t)(b*HH + h0 + ro))*WW + w0 + co;
    if (isbf) ((__hip_bfloat16*)outv)[oi] = __float2bfloat16(t);
    else      ((float*)outv)[oi] = t;
  }
}

extern "C" void kernel_launch(void* const* d_in, const int* in_sizes, int n_in,
                              void* d_out, int out_size, void* d_ws, size_t ws_size,
                              hipStream_t stream) {
  (void)in_sizes; (void)n_in; (void)out_size;
  if (ws_size < XB_BYTES + WB_BYTES + 16) return;

  const void* x  = d_in[0];
  const void* w  = d_in[1];
  const void* bias = d_in[2];
  u16* xb = (u16*)d_ws;
  u16* wb = (u16*)((char*)d_ws + XB_BYTES);

  prep_all<<<NPX + 288, 256, 0, stream>>>(x, w, xb, wb);
  conv_min_kernel<<<6*56*BATCH, 256, 0, stream>>>(xb, wb, bias, d_out, x);
}